// Round 7
// baseline (210.650 us; speedup 1.0000x reference)
//
#include <hip/hip_runtime.h>
#include <hip/hip_bf16.h>

// NT-Xent / InfoNCE loss. features [8192,1024] fp32 -> scalar fp32.
// normalize->bf16, SYMMETRIC fused MFMA GEMM over upper-triangle tiles
// (2080 of 4096), fixed-max logsumexp (unit rows => sim<=1), atomics for
// row+col denominators. Persistent blocks + atomic work queue: 1280 blocks
// (5/CU) dynamically grab tiles -> no cohort quantization, ~1-tile tail.

#define NROWS 8192
#define DDIM  1024
#define BHALF 4096            // positive index = row ^ BHALF
#define ISCALE 14.2857142857142857f  // 1/0.07 == fixed logsumexp max M0

#define BM 128
#define BN 128
#define BK 64
#define KSTEPS (DDIM / BK)            // 16
#define TGRID (NROWS / BM)            // 64
#define NTILES (TGRID * (TGRID + 1) / 2)  // 2080 upper-triangle tiles
#define NPERS 1280                    // persistent blocks, 5/CU

typedef float f32x4 __attribute__((ext_vector_type(4)));
typedef short s16x8 __attribute__((ext_vector_type(8)));
typedef __bf16 bf16x8 __attribute__((ext_vector_type(8)));

// ---- MFMA signature hedge: builtin takes either short8 or bf16x8 ----
template <typename V>
__device__ auto mfma_sel(V a, V b, f32x4 c, int)
    -> decltype(__builtin_amdgcn_mfma_f32_16x16x32_bf16(a, b, c, 0, 0, 0)) {
  return __builtin_amdgcn_mfma_f32_16x16x32_bf16(a, b, c, 0, 0, 0);
}
template <typename V>
__device__ f32x4 mfma_sel(V a, V b, f32x4 c, long) {
  return __builtin_amdgcn_mfma_f32_16x16x32_bf16(
      __builtin_bit_cast(bf16x8, a), __builtin_bit_cast(bf16x8, b), c, 0, 0, 0);
}
__device__ inline f32x4 MFMA(s16x8 a, s16x8 b, f32x4 c) {
  return mfma_sel(a, b, c, 0);
}

__device__ inline unsigned short f2bf(float x) {
  unsigned int b = __builtin_bit_cast(unsigned int, x);
  b += 0x7FFFu + ((b >> 16) & 1u);   // RNE
  return (unsigned short)(b >> 16);
}

// --- kernel 1: L2-normalize rows (wave-per-row) + zero s_accum & counter ---
__global__ __launch_bounds__(256)
void norm_kernel(const float* __restrict__ in, unsigned short* __restrict__ out,
                 float* __restrict__ s_accum, int* __restrict__ counter) {
  if (blockIdx.x == 0 && threadIdx.x == 0) *counter = 0;
  int gid = blockIdx.x * 256 + threadIdx.x;
  if (gid < NROWS) s_accum[gid] = 0.f;     // zero denominators for atomics

  int row = blockIdx.x * 4 + (threadIdx.x >> 6);   // 2048 blocks x 4 waves
  int lane = threadIdx.x & 63;
  const float4* r4 = (const float4*)(in + (size_t)row * DDIM);
  float4 v0 = r4[lane], v1 = r4[lane + 64], v2 = r4[lane + 128],
         v3 = r4[lane + 192];
  float ss = v0.x * v0.x + v0.y * v0.y + v0.z * v0.z + v0.w * v0.w +
             v1.x * v1.x + v1.y * v1.y + v1.z * v1.z + v1.w * v1.w +
             v2.x * v2.x + v2.y * v2.y + v2.z * v2.z + v2.w * v2.w +
             v3.x * v3.x + v3.y * v3.y + v3.z * v3.z + v3.w * v3.w;
  #pragma unroll
  for (int m = 1; m < 64; m <<= 1) ss += __shfl_xor(ss, m, 64);
  float inv = 1.0f / sqrtf(ss);
  ushort4* o4 = (ushort4*)(out + (size_t)row * DDIM);
  ushort4 o;
  o.x = f2bf(v0.x * inv); o.y = f2bf(v0.y * inv);
  o.z = f2bf(v0.z * inv); o.w = f2bf(v0.w * inv); o4[lane] = o;
  o.x = f2bf(v1.x * inv); o.y = f2bf(v1.y * inv);
  o.z = f2bf(v1.z * inv); o.w = f2bf(v1.w * inv); o4[lane + 64] = o;
  o.x = f2bf(v2.x * inv); o.y = f2bf(v2.y * inv);
  o.z = f2bf(v2.z * inv); o.w = f2bf(v2.w * inv); o4[lane + 128] = o;
  o.x = f2bf(v3.x * inv); o.y = f2bf(v3.y * inv);
  o.z = f2bf(v3.z * inv); o.w = f2bf(v3.w * inv); o4[lane + 192] = o;
}

// ---- staging: linear LDS dest (global_load_lds), swizzled global source ---
// LDS tile layout: 128 rows x 128 bytes; 16B slot s of row r holds
// k-elements c*8..c*8+7 where c = s ^ (r&7).  Read applies the same XOR.
__device__ inline void stage_tile(const unsigned short* __restrict__ f,
                                  unsigned short* lds, int row0, int kbase,
                                  int w, int lane) {
  #pragma unroll
  for (int i = 0; i < 4; ++i) {
    int q = w * 4 + i;                 // 16 wave-issues of 1024B per tile
    int r = q * 8 + (lane >> 3);
    int slot = lane & 7;
    int c = slot ^ (r & 7);
    const unsigned short* g = f + (size_t)(row0 + r) * DDIM + kbase + c * 8;
    __builtin_amdgcn_global_load_lds(
        (const __attribute__((address_space(1))) void*)g,
        (__attribute__((address_space(3))) void*)(lds + q * 512), 16, 0, 0);
  }
}

// ------- kernel 2: upper-triangle fused sim GEMM + fixed-max expsum -------
// Persistent: each block pulls tile indices from a global atomic counter.
// Triangle (rt, ct>=rt) enumerated via 32x65 rect: idx -> p=idx/65, q=idx%65;
// q < 64-p -> (p, p+q); else (63-p, q-1). Runs of equal rt => A-panel reuse.
__global__ __launch_bounds__(256, 5)
void simloss_kernel(const unsigned short* __restrict__ f,
                    float* __restrict__ s_accum,
                    float* __restrict__ pos_out,
                    int* __restrict__ counter) {
  __shared__ __align__(16) unsigned short As[BM * BK];  // 16 KB
  __shared__ __align__(16) unsigned short Bs[BN * BK];  // 16 KB
  __shared__ int tileIdxSh;

  int tid = threadIdx.x;
  int lane = tid & 63;
  int w = tid >> 6;        // 4 waves
  int wm = w >> 1, wn = w & 1;

  for (;;) {
    if (tid == 0) tileIdxSh = atomicAdd(counter, 1);
    __syncthreads();                      // broadcast + protects As/Bs reuse
    int idx = tileIdxSh;
    if (idx >= NTILES) break;

    int p = idx / 65, q = idx - p * 65;   // rect decode
    int rt, ct;
    if (q < 64 - p) { rt = p; ct = p + q; }
    else            { rt = 63 - p; ct = q - 1; }
    int rowBase = rt * BM;
    int colBase = ct * BN;
    bool isDiag = (rt == ct);
    bool hasPos = (colBase == (rowBase ^ BHALF));

    f32x4 acc[4][4];
    #pragma unroll
    for (int i = 0; i < 4; ++i)
      #pragma unroll
      for (int j = 0; j < 4; ++j) acc[i][j] = (f32x4){0.f, 0.f, 0.f, 0.f};

    for (int kt = 0; kt < KSTEPS; ++kt) {
      if (kt) __syncthreads();             // prior reads of As/Bs done
      stage_tile(f, As, rowBase, kt * BK, w, lane);
      stage_tile(f, Bs, colBase, kt * BK, w, lane);
      __syncthreads();                     // staged data visible

      #pragma unroll
      for (int kk = 0; kk < 2; ++kk) {     // two K=32 sub-steps of BK=64
        int cs = (lane >> 4) + kk * 4;     // 16B slot index of k-elems
        s16x8 bfr[4];
        #pragma unroll
        for (int fn = 0; fn < 4; ++fn) {
          int r = wn * 64 + fn * 16 + (lane & 15);
          bfr[fn] = *(const s16x8*)((const char*)Bs + r * 128 +
                                    ((cs ^ (r & 7)) << 4));
        }
        #pragma unroll
        for (int fm = 0; fm < 4; ++fm) {
          int r = wm * 64 + fm * 16 + (lane & 15);
          s16x8 a = *(const s16x8*)((const char*)As + r * 128 +
                                    ((cs ^ (r & 7)) << 4));
          #pragma unroll
          for (int fn = 0; fn < 4; ++fn)
            acc[fm][fn] = MFMA(a, bfr[fn], acc[fm][fn]);
        }
      }
    }

    // epilogue: e = exp(x - M0); row-sums and (off-diag) col-sums.
    float s_row[16], s_col[4];
    #pragma unroll
    for (int i = 0; i < 16; ++i) s_row[i] = 0.f;
    #pragma unroll
    for (int i = 0; i < 4; ++i) s_col[i] = 0.f;

    if (isDiag | hasPos) {
      #pragma unroll
      for (int fm = 0; fm < 4; ++fm) {
        #pragma unroll
        for (int j = 0; j < 4; ++j) {
          int R = rowBase + wm * 64 + fm * 16 + ((lane >> 4) << 2) + j;
          #pragma unroll
          for (int fn = 0; fn < 4; ++fn) {
            int C = colBase + wn * 64 + fn * 16 + (lane & 15);
            float x = acc[fm][fn][j] * ISCALE;
            float e = __expf(x - ISCALE);
            if (C == R) e = 0.f;                        // self-mask (diag)
            if (hasPos && C == (R ^ BHALF)) {           // positive capture
              pos_out[R] = x;                           // sim[R][C]
              pos_out[C] = x;                           // sim[C][R] == sim[R][C]
            }
            s_row[fm * 4 + j] += e;
            s_col[fn] += e;
          }
        }
      }
    } else {
      #pragma unroll
      for (int fm = 0; fm < 4; ++fm) {
        #pragma unroll
        for (int j = 0; j < 4; ++j) {
          #pragma unroll
          for (int fn = 0; fn < 4; ++fn) {
            float e = __expf(fmaf(acc[fm][fn][j], ISCALE, -ISCALE));
            s_row[fm * 4 + j] += e;
            s_col[fn] += e;
          }
        }
      }
    }

    // row-sums: reduce across cols (lane&15), one atomic per row per wave.
    #pragma unroll
    for (int fm = 0; fm < 4; ++fm) {
      #pragma unroll
      for (int j = 0; j < 4; ++j) {
        float sv = s_row[fm * 4 + j];
        sv += __shfl_xor(sv, 1, 64);
        sv += __shfl_xor(sv, 2, 64);
        sv += __shfl_xor(sv, 4, 64);
        sv += __shfl_xor(sv, 8, 64);
        if ((lane & 15) == 0) {
          int R = rowBase + wm * 64 + fm * 16 + ((lane >> 4) << 2) + j;
          atomicAdd(&s_accum[R], sv);
        }
      }
    }
    // col-sums: reduce across rows, skip on diagonal tiles (diag already
    // holds both (i,j) and (j,i) in its row-sums).
    if (!isDiag) {
      #pragma unroll
      for (int fn = 0; fn < 4; ++fn) {
        float c = s_col[fn];
        c += __shfl_xor(c, 16, 64);
        c += __shfl_xor(c, 32, 64);
        if (lane < 16) {
          int C = colBase + wn * 64 + fn * 16 + lane;
          atomicAdd(&s_accum[C], c);
        }
      }
    }
  }
}

// ---------------- kernel 3a: per-row loss, 64-block partial sums ----------
__global__ void finalize1_kernel(const float* __restrict__ s_accum,
                                 const float* __restrict__ pos,
                                 float* __restrict__ part2) {
  int r = blockIdx.x * 128 + threadIdx.x;   // 64 blocks x 128 threads
  float local = (ISCALE + logf(s_accum[r])) - pos[r];
  #pragma unroll
  for (int m = 1; m < 64; m <<= 1) local += __shfl_xor(local, m, 64);
  __shared__ float red[2];
  if ((threadIdx.x & 63) == 0) red[threadIdx.x >> 6] = local;
  __syncthreads();
  if (threadIdx.x == 0) part2[blockIdx.x] = red[0] + red[1];
}

// ---------------- kernel 3b: merge 64 partials, mean ----------------------
__global__ void finalize2_kernel(const float* __restrict__ part2,
                                 float* __restrict__ out) {
  float v = part2[threadIdx.x];             // 64 threads
  #pragma unroll
  for (int m = 1; m < 64; m <<= 1) v += __shfl_xor(v, m, 64);
  if (threadIdx.x == 0) out[0] = v / (float)NROWS;
}

extern "C" void kernel_launch(void* const* d_in, const int* in_sizes, int n_in,
                              void* d_out, int out_size, void* d_ws,
                              size_t ws_size, hipStream_t stream) {
  const float* feats = (const float*)d_in[0];
  char* ws = (char*)d_ws;
  unsigned short* fbf = (unsigned short*)ws;                      // 16 MB
  float* s_accum = (float*)(ws + (size_t)NROWS * DDIM * 2);       // 32 KB
  float* pos     = (float*)((char*)s_accum + (size_t)NROWS * 4);
  float* part2   = (float*)((char*)pos + (size_t)NROWS * 4);
  int*   counter = (int*)((char*)part2 + 64 * 4);
  float* out = (float*)d_out;

  norm_kernel<<<NROWS / 4, 256, 0, stream>>>(feats, fbf, s_accum, counter);
  simloss_kernel<<<NPERS, 256, 0, stream>>>(fbf, s_accum, pos, counter);
  finalize1_kernel<<<64, 128, 0, stream>>>(s_accum, pos, part2);
  finalize2_kernel<<<1, 64, 0, stream>>>(part2, out);
}

// Round 8
// 130.603 us; speedup vs baseline: 1.6129x; 1.6129x over previous
//
#include <hip/hip_runtime.h>
#include <hip/hip_bf16.h>

// NT-Xent / InfoNCE loss. features [8192,1024] fp32 -> scalar fp32.
// normalize -> int8 (fixed scale S=512, exact integer dot), SYMMETRIC fused
// i8-MFMA GEMM over upper-triangle 128x128 tiles (2080 of 4096), fixed-max
// logsumexp (unit rows => sim<=1), atomics for row+col denominators.
// i8 BK=128 tile is byte-identical geometry to the proven bf16 BK=64 tile.

#define NROWS 8192
#define DDIM  1024
#define BHALF 4096            // positive index = row ^ BHALF
#define ISCALE 14.2857142857142857f  // 1/0.07 == fixed logsumexp max M0
#define QSCALE 512.0f         // int8 quantization scale
#define K1 (ISCALE / (QSCALE * QSCALE))  // dot_i32 -> logit

#define BM 128
#define BN 128
#define BKB 128               // K-bytes per step = 128 i8 elems
#define KSTEPS (DDIM / 128)           // 8
#define TGRID (NROWS / BM)            // 64
#define NTILES (TGRID * (TGRID + 1) / 2)  // 2080 upper-triangle tiles

typedef float f32x4 __attribute__((ext_vector_type(4)));
typedef int   i32x4 __attribute__((ext_vector_type(4)));

// ---- i8 MFMA hedge: expected signature (V4i, V4i, V4i, Ii, Ii, Ii) ----
template <typename V>
__device__ auto mfma_i8_sel(V a, V b, i32x4 c, int)
    -> decltype(__builtin_amdgcn_mfma_i32_16x16x64_i8(a, b, c, 0, 0, 0)) {
  return __builtin_amdgcn_mfma_i32_16x16x64_i8(a, b, c, 0, 0, 0);
}
__device__ inline i32x4 MFMA_I8(i32x4 a, i32x4 b, i32x4 c) {
  return mfma_i8_sel(a, b, c, 0);
}

// --- kernel 1: L2-normalize rows -> i8 (wave-per-row), zero s_accum & out --
__global__ __launch_bounds__(256)
void norm_kernel(const float* __restrict__ in, signed char* __restrict__ out,
                 float* __restrict__ s_accum, float* __restrict__ loss_out) {
  if (blockIdx.x == 0 && threadIdx.x == 0) loss_out[0] = 0.f;
  int gid = blockIdx.x * 256 + threadIdx.x;
  if (gid < NROWS) s_accum[gid] = 0.f;     // zero denominators for atomics

  int row = blockIdx.x * 4 + (threadIdx.x >> 6);   // 2048 blocks x 4 waves
  int lane = threadIdx.x & 63;
  const float4* r4 = (const float4*)(in + (size_t)row * DDIM);
  float4 v[4];
  #pragma unroll
  for (int i = 0; i < 4; ++i) v[i] = r4[lane * 4 + i];   // 64B consecutive
  float ss = 0.f;
  #pragma unroll
  for (int i = 0; i < 4; ++i)
    ss += v[i].x * v[i].x + v[i].y * v[i].y + v[i].z * v[i].z + v[i].w * v[i].w;
  #pragma unroll
  for (int m = 1; m < 64; m <<= 1) ss += __shfl_xor(ss, m, 64);
  float inv = QSCALE / sqrtf(ss);

  int words[4];
  #pragma unroll
  for (int i = 0; i < 4; ++i) {
    int q0 = max(-127, min(127, __float2int_rn(v[i].x * inv)));
    int q1 = max(-127, min(127, __float2int_rn(v[i].y * inv)));
    int q2 = max(-127, min(127, __float2int_rn(v[i].z * inv)));
    int q3 = max(-127, min(127, __float2int_rn(v[i].w * inv)));
    words[i] = (q0 & 255) | ((q1 & 255) << 8) | ((q2 & 255) << 16) | (q3 << 24);
  }
  int4 o = make_int4(words[0], words[1], words[2], words[3]);
  *(int4*)(out + (size_t)row * DDIM + lane * 16) = o;    // 16B consecutive
}

// ---- staging: linear LDS dest (global_load_lds), swizzled global source ---
// LDS tile: 128 rows x 128 bytes; 16B slot s of row r holds k-bytes
// c*16..c*16+15 where c = s ^ (r&7). Read applies the same XOR.
__device__ inline void stage_tile(const signed char* __restrict__ f,
                                  signed char* lds, int row0, int kbyte,
                                  int w, int lane) {
  #pragma unroll
  for (int i = 0; i < 4; ++i) {
    int q = w * 4 + i;                 // 16 wave-issues of 1024B per tile
    int r = q * 8 + (lane >> 3);
    int slot = lane & 7;
    int c = slot ^ (r & 7);
    const signed char* g = f + (size_t)(row0 + r) * DDIM + kbyte + c * 16;
    __builtin_amdgcn_global_load_lds(
        (const __attribute__((address_space(1))) void*)g,
        (__attribute__((address_space(3))) void*)(lds + q * 1024), 16, 0, 0);
  }
}

// ------- kernel 2: upper-triangle fused sim GEMM (i8) + fixed-max expsum ---
// Triangle (rt, ct>=rt) via 32x65 rect: idx -> p=idx/65, q=idx%65;
// q < 64-p -> (p, p+q); else (63-p, q-1).
__global__ __launch_bounds__(256, 4)
void simloss_kernel(const signed char* __restrict__ f,
                    float* __restrict__ s_accum,
                    float* __restrict__ pos_out) {
  __shared__ __align__(16) signed char As[BM * BKB];  // 16 KB
  __shared__ __align__(16) signed char Bs[BN * BKB];  // 16 KB

  // XCD-aware swizzle: 2080 % 8 == 0 -> simple bijective form.
  int bid = blockIdx.x;
  int idx = (bid & 7) * (NTILES / 8) + (bid >> 3);
  int p = idx / 65, q = idx - p * 65;   // rect decode
  int rt, ct;
  if (q < 64 - p) { rt = p; ct = p + q; }
  else            { rt = 63 - p; ct = q - 1; }
  int rowBase = rt * BM;
  int colBase = ct * BN;
  bool isDiag = (rt == ct);
  bool hasPos = (colBase == (rowBase ^ BHALF));

  int tid = threadIdx.x;
  int lane = tid & 63;
  int w = tid >> 6;        // 4 waves
  int wm = w >> 1, wn = w & 1;

  i32x4 acc[4][4];
  #pragma unroll
  for (int i = 0; i < 4; ++i)
    #pragma unroll
    for (int j = 0; j < 4; ++j) acc[i][j] = (i32x4){0, 0, 0, 0};

  for (int kt = 0; kt < KSTEPS; ++kt) {
    __syncthreads();                       // prior reads of As/Bs done
    stage_tile(f, As, rowBase, kt * BKB, w, lane);
    stage_tile(f, Bs, colBase, kt * BKB, w, lane);
    __syncthreads();                       // staged data visible

    #pragma unroll
    for (int kk = 0; kk < 2; ++kk) {       // two K=64 sub-steps of BK=128
      int cs = (lane >> 4) + kk * 4;       // 16B slot index of k-bytes
      i32x4 bfr[4];
      #pragma unroll
      for (int fn = 0; fn < 4; ++fn) {
        int r = wn * 64 + fn * 16 + (lane & 15);
        bfr[fn] = *(const i32x4*)(Bs + r * 128 + ((cs ^ (r & 7)) << 4));
      }
      #pragma unroll
      for (int fm = 0; fm < 4; ++fm) {
        int r = wm * 64 + fm * 16 + (lane & 15);
        i32x4 a = *(const i32x4*)(As + r * 128 + ((cs ^ (r & 7)) << 4));
        #pragma unroll
        for (int fn = 0; fn < 4; ++fn)
          acc[fm][fn] = MFMA_I8(a, bfr[fn], acc[fm][fn]);
      }
    }
  }

  // epilogue: x = dot*K1; e = exp(x - M0); row-sums and (off-diag) col-sums.
  float s_row[16], s_col[4];
  #pragma unroll
  for (int i = 0; i < 16; ++i) s_row[i] = 0.f;
  #pragma unroll
  for (int i = 0; i < 4; ++i) s_col[i] = 0.f;

  if (isDiag | hasPos) {
    #pragma unroll
    for (int fm = 0; fm < 4; ++fm) {
      #pragma unroll
      for (int j = 0; j < 4; ++j) {
        int R = rowBase + wm * 64 + fm * 16 + ((lane >> 4) << 2) + j;
        #pragma unroll
        for (int fn = 0; fn < 4; ++fn) {
          int C = colBase + wn * 64 + fn * 16 + (lane & 15);
          float x = (float)acc[fm][fn][j] * K1;
          float e = __expf(x - ISCALE);
          if (C == R) e = 0.f;                        // self-mask (diag)
          if (hasPos && C == (R ^ BHALF)) {           // positive capture
            pos_out[R] = x;                           // sim[R][C]
            pos_out[C] = x;                           // sim[C][R] == sim[R][C]
          }
          s_row[fm * 4 + j] += e;
          s_col[fn] += e;
        }
      }
    }
  } else {
    #pragma unroll
    for (int fm = 0; fm < 4; ++fm) {
      #pragma unroll
      for (int j = 0; j < 4; ++j) {
        #pragma unroll
        for (int fn = 0; fn < 4; ++fn) {
          float e = __expf(fmaf((float)acc[fm][fn][j], K1, -ISCALE));
          s_row[fm * 4 + j] += e;
          s_col[fn] += e;
        }
      }
    }
  }

  // row-sums: reduce across cols (lane&15), one atomic per row per wave.
  #pragma unroll
  for (int fm = 0; fm < 4; ++fm) {
    #pragma unroll
    for (int j = 0; j < 4; ++j) {
      float sv = s_row[fm * 4 + j];
      sv += __shfl_xor(sv, 1, 64);
      sv += __shfl_xor(sv, 2, 64);
      sv += __shfl_xor(sv, 4, 64);
      sv += __shfl_xor(sv, 8, 64);
      if ((lane & 15) == 0) {
        int R = rowBase + wm * 64 + fm * 16 + ((lane >> 4) << 2) + j;
        atomicAdd(&s_accum[R], sv);
      }
    }
  }
  // col-sums: reduce across rows, skip on diagonal tiles (diag already
  // holds both (i,j) and (j,i) in its row-sums).
  if (!isDiag) {
    #pragma unroll
    for (int fn = 0; fn < 4; ++fn) {
      float c = s_col[fn];
      c += __shfl_xor(c, 16, 64);
      c += __shfl_xor(c, 32, 64);
      if (lane < 16) {
        int C = colBase + wn * 64 + fn * 16 + lane;
        atomicAdd(&s_accum[C], c);
      }
    }
  }
}

// ------- kernel 3: per-row loss, block partials, atomic mean into out -----
__global__ void finalize_kernel(const float* __restrict__ s_accum,
                                const float* __restrict__ pos,
                                float* __restrict__ out) {
  int r = blockIdx.x * 128 + threadIdx.x;   // 64 blocks x 128 threads
  float local = (ISCALE + logf(s_accum[r])) - pos[r];
  #pragma unroll
  for (int m = 1; m < 64; m <<= 1) local += __shfl_xor(local, m, 64);
  __shared__ float red[2];
  if ((threadIdx.x & 63) == 0) red[threadIdx.x >> 6] = local;
  __syncthreads();
  if (threadIdx.x == 0)
    atomicAdd(out, (red[0] + red[1]) * (1.0f / (float)NROWS));
}

extern "C" void kernel_launch(void* const* d_in, const int* in_sizes, int n_in,
                              void* d_out, int out_size, void* d_ws,
                              size_t ws_size, hipStream_t stream) {
  const float* feats = (const float*)d_in[0];
  char* ws = (char*)d_ws;
  signed char* f8  = (signed char*)ws;                            // 8 MB
  float* s_accum = (float*)(ws + (size_t)NROWS * DDIM);           // 32 KB
  float* pos     = (float*)((char*)s_accum + (size_t)NROWS * 4);
  float* out = (float*)d_out;

  norm_kernel<<<NROWS / 4, 256, 0, stream>>>(feats, f8, s_accum, out);
  simloss_kernel<<<NTILES, 256, 0, stream>>>(f8, s_accum, pos);
  finalize_kernel<<<64, 128, 0, stream>>>(s_accum, pos, out);
}